// Round 1
// baseline (17.501 us; speedup 1.0000x reference)
//
#include <hip/hip_runtime.h>
#include <hip/hip_bf16.h>

typedef __attribute__((ext_vector_type(4))) float f32x4;
typedef __attribute__((ext_vector_type(8))) short short8;

#define NA 1024
#define NB 1024
#define KF 256
#define DIM 128

// ---------------- Phase 1: fk = X @ feats^T, epilogue -> P (relu, bf16), M (mask, bf16) ----
// 8 rows per block, one feats column per thread (256 threads == 256 columns).
// f64 accumulation of exact f32 products => sign of b_fk matches numpy reference.
__global__ __launch_bounds__(256) void proj_kernel(
    const float* __restrict__ a, const float* __restrict__ b,
    const float* __restrict__ feats,
    __hip_bfloat16* __restrict__ P, __hip_bfloat16* __restrict__ M)
{
    __shared__ float X[8][DIM];
    const int t = threadIdx.x;
    const int row0 = blockIdx.x * 8;
    const bool isA = (row0 < NA);
    const float* src = isA ? a : b;
    const int r0 = isA ? row0 : (row0 - NA);

    // cooperative load: 8 rows * 128 f32 = 256 float4, one per thread
    {
        const f32x4* s4 = (const f32x4*)(src + (size_t)r0 * DIM);
        ((f32x4*)&X[0][0])[t] = s4[t];
    }
    __syncthreads();

    const int k = t;  // feature column
    const f32x4* f4 = (const f32x4*)(feats + (size_t)k * DIM);
    double acc[8];
#pragma unroll
    for (int r = 0; r < 8; ++r) acc[r] = 0.0;

#pragma unroll 4
    for (int d4 = 0; d4 < DIM / 4; ++d4) {
        f32x4 f = f4[d4];
#pragma unroll
        for (int j = 0; j < 4; ++j) {
            double fd = (double)f[j];
#pragma unroll
            for (int r = 0; r < 8; ++r)
                acc[r] = fma(fd, (double)X[r][d4 * 4 + j], acc[r]);
        }
    }

    if (isA) {
#pragma unroll
        for (int r = 0; r < 8; ++r) {
            float v = (acc[r] > 0.0) ? (float)acc[r] : 0.0f;
            P[(size_t)(r0 + r) * KF + k] = __float2bfloat16(v);
        }
    } else {
#pragma unroll
        for (int r = 0; r < 8; ++r) {
            float v = (acc[r] <= 0.0) ? 1.0f : 0.0f;
            M[(size_t)(r0 + r) * KF + k] = __float2bfloat16(v);
        }
    }
}

// ---------------- Phase 2: out = P @ M^T, bf16 MFMA, f32 accumulate ----------------
// 64x64 tile per block, 4 waves as 2x2, each wave 32x32 = 2x2 fragments of 16x16x32.
// Whole K=256 strip staged in LDS once; rows padded to 264 shorts (528 B -> stride
// == 4 banks mod 32 -> effectively conflict-free ds_read_b128).
__global__ __launch_bounds__(256) void gemm_kernel(
    const __hip_bfloat16* __restrict__ P, const __hip_bfloat16* __restrict__ M,
    float* __restrict__ out)
{
    __shared__ short LA[64][264];
    __shared__ short LB[64][264];
    const int t = threadIdx.x;
    const int row0 = blockIdx.y * 64;
    const int col0 = blockIdx.x * 64;
    const short* Pa = (const short*)P;
    const short* Mb = (const short*)M;

    // stage both 64x256 bf16 strips: 2048 16B-chunks each, 8 per thread
#pragma unroll
    for (int i = 0; i < 8; ++i) {
        int c = t + i * 256;
        int row = c >> 5;          // 32 chunks per row
        int c8 = (c & 31) << 3;    // element offset
        *(short8*)&LA[row][c8] = *(const short8*)(Pa + (size_t)(row0 + row) * KF + c8);
        *(short8*)&LB[row][c8] = *(const short8*)(Mb + (size_t)(col0 + row) * KF + c8);
    }
    __syncthreads();

    const int lane = t & 63;
    const int wid = t >> 6;
    const int wr = (wid >> 1) * 32;   // wave row offset in tile
    const int wc = (wid & 1) * 32;    // wave col offset in tile
    const int fr = lane & 15;         // A-row / B-col within fragment
    const int fq = lane >> 4;         // k sub-block (0..3)

    f32x4 acc[2][2];
#pragma unroll
    for (int m = 0; m < 2; ++m)
#pragma unroll
        for (int n = 0; n < 2; ++n)
            acc[m][n] = (f32x4){0.f, 0.f, 0.f, 0.f};

#pragma unroll
    for (int kk = 0; kk < KF / 32; ++kk) {
        const int kb = kk * 32 + fq * 8;
        short8 a0 = *(const short8*)&LA[wr + fr][kb];
        short8 a1 = *(const short8*)&LA[wr + 16 + fr][kb];
        short8 b0 = *(const short8*)&LB[wc + fr][kb];
        short8 b1 = *(const short8*)&LB[wc + 16 + fr][kb];
        acc[0][0] = __builtin_amdgcn_mfma_f32_16x16x32_bf16(a0, b0, acc[0][0], 0, 0, 0);
        acc[0][1] = __builtin_amdgcn_mfma_f32_16x16x32_bf16(a0, b1, acc[0][1], 0, 0, 0);
        acc[1][0] = __builtin_amdgcn_mfma_f32_16x16x32_bf16(a1, b0, acc[1][0], 0, 0, 0);
        acc[1][1] = __builtin_amdgcn_mfma_f32_16x16x32_bf16(a1, b1, acc[1][1], 0, 0, 0);
    }

    // D layout (verified m89): col = lane&15, row = (lane>>4)*4 + reg
#pragma unroll
    for (int m = 0; m < 2; ++m)
#pragma unroll
        for (int n = 0; n < 2; ++n)
#pragma unroll
            for (int r = 0; r < 4; ++r) {
                int row = row0 + wr + m * 16 + fq * 4 + r;
                int col = col0 + wc + n * 16 + fr;
                out[(size_t)row * NB + col] = acc[m][n][r];
            }
}

extern "C" void kernel_launch(void* const* d_in, const int* in_sizes, int n_in,
                              void* d_out, int out_size, void* d_ws, size_t ws_size,
                              hipStream_t stream) {
    const float* a = (const float*)d_in[0];
    const float* b = (const float*)d_in[1];
    const float* feats = (const float*)d_in[2];
    float* out = (float*)d_out;
    __hip_bfloat16* P = (__hip_bfloat16*)d_ws;                 // 1024*256 bf16 = 512 KB
    __hip_bfloat16* M = P + (size_t)NA * KF;                   // +512 KB

    proj_kernel<<<dim3((NA + NB) / 8), dim3(256), 0, stream>>>(a, b, feats, P, M);
    gemm_kernel<<<dim3(NB / 64, NA / 64), dim3(256), 0, stream>>>(P, M, out);
}

// Round 2
// 15.912 us; speedup vs baseline: 1.0999x; 1.0999x over previous
//
#include <hip/hip_runtime.h>
#include <hip/hip_bf16.h>

typedef __attribute__((ext_vector_type(4))) float f32x4;
typedef __attribute__((ext_vector_type(2))) double f64x2;
typedef __attribute__((ext_vector_type(8))) short short8;

#define NA 1024
#define NB 1024
#define KF 256
#define DIM 128

// ---------------- Phase 1: fk = X @ feats^T -> P (relu, bf16), M (mask<=0, bf16) ----
// Block = 32 rows x 64 cols of fk. Grid = 64 row-blocks x 4 col-blocks = 256 (1/CU).
// X and feats slice staged into LDS as f64 (convert once at staging; no in-loop cvt).
// Thread: 4 rows x 2 cols. X reads = 2-distinct-addr broadcasts (free); feats reads =
// strided ds_read_b128 at row stride 130 f64 = 65 quads == 1 mod 8 -> conflict-free.
#define RB 32
#define CB 64
#define FPAD 130

__global__ __launch_bounds__(256) void proj_kernel(
    const float* __restrict__ a, const float* __restrict__ b,
    const float* __restrict__ feats,
    __hip_bfloat16* __restrict__ P, __hip_bfloat16* __restrict__ M)
{
    __shared__ double Xd[RB][FPAD];   // 33,280 B
    __shared__ double Fd[CB][FPAD];   // 66,560 B (total ~97.5 KB, fits 160 KB)

    const int t = threadIdx.x;
    const int rowBlk = blockIdx.x >> 2;
    const int colBlk = blockIdx.x & 3;
    const int row0 = rowBlk * RB;      // row in concatenated [a;b]
    const int col0 = colBlk * CB;

    const bool isA = row0 < NA;
    const float* __restrict__ src = isA ? a : b;
    const int r0 = isA ? row0 : row0 - NA;

    // stage X: 32 rows x 128 f32 = 1024 f32x4 (coalesced), 4 per thread, cvt to f64
#pragma unroll
    for (int i = 0; i < 4; ++i) {
        int idx = t + i * 256;
        int r = idx >> 5, c4 = idx & 31;
        f32x4 v = ((const f32x4*)(src + (size_t)(r0 + r) * DIM))[c4];
#pragma unroll
        for (int j = 0; j < 4; ++j) Xd[r][c4 * 4 + j] = (double)v[j];
    }
    // stage feats slice: 64 rows x 128 f32 = 2048 f32x4 (coalesced), 8 per thread
#pragma unroll
    for (int i = 0; i < 8; ++i) {
        int idx = t + i * 256;
        int r = idx >> 5, c4 = idx & 31;
        f32x4 v = ((const f32x4*)(feats + (size_t)(col0 + r) * DIM))[c4];
#pragma unroll
        for (int j = 0; j < 4; ++j) Fd[r][c4 * 4 + j] = (double)v[j];
    }
    __syncthreads();

    const int rg = t >> 5;   // 0..7 -> rows 4rg..4rg+3
    const int cl = t & 31;   // cols cl, cl+32

    double acc[4][2] = {{0.0, 0.0}, {0.0, 0.0}, {0.0, 0.0}, {0.0, 0.0}};

#pragma unroll 2
    for (int d = 0; d < DIM; d += 4) {
        f64x2 xa[4][2], fa[2][2];
#pragma unroll
        for (int r = 0; r < 4; ++r) {
            xa[r][0] = *(const f64x2*)&Xd[rg * 4 + r][d];
            xa[r][1] = *(const f64x2*)&Xd[rg * 4 + r][d + 2];
        }
        fa[0][0] = *(const f64x2*)&Fd[cl][d];
        fa[0][1] = *(const f64x2*)&Fd[cl][d + 2];
        fa[1][0] = *(const f64x2*)&Fd[cl + 32][d];
        fa[1][1] = *(const f64x2*)&Fd[cl + 32][d + 2];
#pragma unroll
        for (int r = 0; r < 4; ++r)
#pragma unroll
            for (int h = 0; h < 2; ++h)
#pragma unroll
                for (int j = 0; j < 2; ++j) {
                    acc[r][0] = fma(xa[r][h][j], fa[0][h][j], acc[r][0]);
                    acc[r][1] = fma(xa[r][h][j], fa[1][h][j], acc[r][1]);
                }
    }

    if (isA) {
#pragma unroll
        for (int r = 0; r < 4; ++r) {
            size_t grow = (size_t)(r0 + rg * 4 + r) * KF;
            float v0 = (acc[r][0] > 0.0) ? (float)acc[r][0] : 0.0f;
            float v1 = (acc[r][1] > 0.0) ? (float)acc[r][1] : 0.0f;
            P[grow + col0 + cl] = __float2bfloat16(v0);
            P[grow + col0 + cl + 32] = __float2bfloat16(v1);
        }
    } else {
#pragma unroll
        for (int r = 0; r < 4; ++r) {
            size_t grow = (size_t)(r0 + rg * 4 + r) * KF;
            float v0 = (acc[r][0] <= 0.0) ? 1.0f : 0.0f;
            float v1 = (acc[r][1] <= 0.0) ? 1.0f : 0.0f;
            M[grow + col0 + cl] = __float2bfloat16(v0);
            M[grow + col0 + cl + 32] = __float2bfloat16(v1);
        }
    }
}

// ---------------- Phase 2: out = P @ M^T, bf16 MFMA, f32 accumulate (unchanged) ------
__global__ __launch_bounds__(256) void gemm_kernel(
    const __hip_bfloat16* __restrict__ P, const __hip_bfloat16* __restrict__ M,
    float* __restrict__ out)
{
    __shared__ short LA[64][264];
    __shared__ short LB[64][264];
    const int t = threadIdx.x;
    const int row0 = blockIdx.y * 64;
    const int col0 = blockIdx.x * 64;
    const short* Pa = (const short*)P;
    const short* Mb = (const short*)M;

#pragma unroll
    for (int i = 0; i < 8; ++i) {
        int c = t + i * 256;
        int row = c >> 5;
        int c8 = (c & 31) << 3;
        *(short8*)&LA[row][c8] = *(const short8*)(Pa + (size_t)(row0 + row) * KF + c8);
        *(short8*)&LB[row][c8] = *(const short8*)(Mb + (size_t)(col0 + row) * KF + c8);
    }
    __syncthreads();

    const int lane = t & 63;
    const int wid = t >> 6;
    const int wr = (wid >> 1) * 32;
    const int wc = (wid & 1) * 32;
    const int fr = lane & 15;
    const int fq = lane >> 4;

    f32x4 acc[2][2];
#pragma unroll
    for (int m = 0; m < 2; ++m)
#pragma unroll
        for (int n = 0; n < 2; ++n)
            acc[m][n] = (f32x4){0.f, 0.f, 0.f, 0.f};

#pragma unroll
    for (int kk = 0; kk < KF / 32; ++kk) {
        const int kb = kk * 32 + fq * 8;
        short8 a0 = *(const short8*)&LA[wr + fr][kb];
        short8 a1 = *(const short8*)&LA[wr + 16 + fr][kb];
        short8 b0 = *(const short8*)&LB[wc + fr][kb];
        short8 b1 = *(const short8*)&LB[wc + 16 + fr][kb];
        acc[0][0] = __builtin_amdgcn_mfma_f32_16x16x32_bf16(a0, b0, acc[0][0], 0, 0, 0);
        acc[0][1] = __builtin_amdgcn_mfma_f32_16x16x32_bf16(a0, b1, acc[0][1], 0, 0, 0);
        acc[1][0] = __builtin_amdgcn_mfma_f32_16x16x32_bf16(a1, b0, acc[1][0], 0, 0, 0);
        acc[1][1] = __builtin_amdgcn_mfma_f32_16x16x32_bf16(a1, b1, acc[1][1], 0, 0, 0);
    }

#pragma unroll
    for (int m = 0; m < 2; ++m)
#pragma unroll
        for (int n = 0; n < 2; ++n)
#pragma unroll
            for (int r = 0; r < 4; ++r) {
                int row = row0 + wr + m * 16 + fq * 4 + r;
                int col = col0 + wc + n * 16 + fr;
                out[(size_t)row * NB + col] = acc[m][n][r];
            }
}

extern "C" void kernel_launch(void* const* d_in, const int* in_sizes, int n_in,
                              void* d_out, int out_size, void* d_ws, size_t ws_size,
                              hipStream_t stream) {
    const float* a = (const float*)d_in[0];
    const float* b = (const float*)d_in[1];
    const float* feats = (const float*)d_in[2];
    float* out = (float*)d_out;
    __hip_bfloat16* P = (__hip_bfloat16*)d_ws;
    __hip_bfloat16* M = P + (size_t)NA * KF;

    proj_kernel<<<dim3(256), dim3(256), 0, stream>>>(a, b, feats, P, M);
    gemm_kernel<<<dim3(NB / 64, NA / 64), dim3(256), 0, stream>>>(P, M, out);
}